// Round 11
// baseline (245.601 us; speedup 1.0000x reference)
//
#include <hip/hip_runtime.h>
#include <stdint.h>

#define Bv 8
#define Cv 64
#define Lv 65536
#define TPB 512
#define COLS 256                      // contiguous cols per block (1KB/row bursts)
#define BLKS_PER_B (Lv / COLS)        // 256
#define GRID1 (Bv * BLKS_PER_B)       // 2048

// workspace: partials 2*2048 floats (16 KiB) + sb 1024 floats (4 KiB) = 20 KiB
// (proven footprint; do not grow)

typedef __attribute__((ext_vector_type(8))) short short8;
typedef __attribute__((ext_vector_type(4))) float f32x4;

#define SSTRIDE 260   // dwords per row: 16B-aligned, 260%32=4 staggers banks

__device__ __forceinline__ uint16_t f2bf(float f) {
    uint32_t u = __float_as_uint(f);
    uint32_t r = u + 0x7FFFu + ((u >> 16) & 1u);   // round-to-nearest-even
    return (uint16_t)(r >> 16);
}
__device__ __forceinline__ uint32_t pack2bf(float lo, float hi) {
    return (uint32_t)f2bf(lo) | ((uint32_t)f2bf(hi) << 16);
}
__device__ __forceinline__ float bf_lo(uint32_t u) { return __uint_as_float(u << 16); }
__device__ __forceinline__ float bf_hi(uint32_t u) { return __uint_as_float(u & 0xFFFF0000u); }

// ---------------------------------------------------------------------------
// Pass 1 (MFMA, K-split): out = relu(Wf·(x ⊙ (Wg·s + 2bg)) + bf + resid)
// R11 vs R10: (1) x staged as bf16 into x_lds during the s staging -> the
// acc = x*g phase between the GEMMs is LDS-only (no global x re-read on the
// critical path); (2) stats via wave shuffle (kills 7 barriers, frees 4KB).
// LDS 67.3KB -> 2 blocks/CU (reg-bound anyway at ~120 regs/wave).
// ---------------------------------------------------------------------------
__global__ void pass1(const float* __restrict__ x, const float* __restrict__ inj0,
                      const float* __restrict__ inj1, const float* __restrict__ resid,
                      const float* __restrict__ gate_w, const float* __restrict__ gate_b,
                      const float* __restrict__ fuse_w, const float* __restrict__ fuse_b,
                      float* __restrict__ out, float* __restrict__ partials)
{
    __shared__ uint32_t s_buf[16 * SSTRIDE];       // 16.6 KB (s, then acc, then epi tile)
    __shared__ uint32_t x_lds[2][16 * SSTRIDE];    // 33.3 KB (x bf16, both K-halves)
    __shared__ uint32_t w_lds[2][64][36];          // 18.4 KB
    __shared__ float cinit[2][64];                 // [0]=2*gate_b, [1]=fuse_b
    __shared__ float wred[16];                     // per-wave stats partials

    const int tid  = threadIdx.x;
    const int lane = tid & 63;
    const int w    = tid >> 6;     // wave 0..7
    const int g    = lane >> 4;    // k-group 0..3
    const int ln   = lane & 15;    // 0..15

    const int b    = blockIdx.x >> 8;
    const int lb   = blockIdx.x & 255;
    const int col0 = lb * COLS;
    const int bCL  = b * (Cv * Lv);

    // ---- stage weights (once): 512 units = 2 mats x 64 rows x 4 k-quads ----
    {
        const int mat = tid >> 8;              // 0=gate, 1=fuse
        const int m   = (tid >> 2) & 63;
        const int k0  = (tid & 3) << 4;
        const float* wsrc = mat ? fuse_w : gate_w;
        const float4* w4 = reinterpret_cast<const float4*>(wsrc + m * 64 + k0);
        uint32_t* dst = &w_lds[mat][m][k0 >> 1];
        #pragma unroll
        for (int q = 0; q < 4; ++q) {
            const float4 v = w4[q];
            dst[2 * q]     = pack2bf(v.x, v.y);
            dst[2 * q + 1] = pack2bf(v.z, v.w);
        }
        if (tid < 64) {
            cinit[0][tid] = 2.0f * gate_b[tid];
            cinit[1][tid] = fuse_b[tid];
        }
    }
    __syncthreads();   // cinit/w_lds visible to all waves

    // ---- GEMM1 (K-split): D1 = Wg . s + 2*gate_b ----
    f32x4 D1[4][2];
    #pragma unroll
    for (int oc = 0; oc < 4; ++oc) {
        const float4 cb = *reinterpret_cast<const float4*>(&cinit[0][16 * oc + 4 * g]);
        D1[oc][0][0] = cb.x; D1[oc][0][1] = cb.y;
        D1[oc][0][2] = cb.z; D1[oc][0][3] = cb.w;
        D1[oc][1] = D1[oc][0];
    }

    #pragma unroll 1
    for (int kh = 0; kh < 2; ++kh) {
        // stage s = i0+i1+2x AND x (both bf16 kpair dwords) for ch [32kh,+32)
        #pragma unroll
        for (int uu = 0; uu < 2; ++uu) {
            const int u  = tid + uu * TPB;
            const int kp = u >> 6;               // 0..15
            const int c  = (u & 63) << 2;        // col 0..252
            const int rA = bCL + (32 * kh + 2 * kp) * Lv + col0 + c;
            const int rB = rA + Lv;
            const float4 xA = *reinterpret_cast<const float4*>(x    + rA);
            const float4 aA = *reinterpret_cast<const float4*>(inj0 + rA);
            const float4 bA = *reinterpret_cast<const float4*>(inj1 + rA);
            const float4 xB = *reinterpret_cast<const float4*>(x    + rB);
            const float4 aB = *reinterpret_cast<const float4*>(inj0 + rB);
            const float4 bB = *reinterpret_cast<const float4*>(inj1 + rB);
            uint4 dw;
            dw.x = pack2bf(aA.x + bA.x + 2.0f * xA.x, aB.x + bB.x + 2.0f * xB.x);
            dw.y = pack2bf(aA.y + bA.y + 2.0f * xA.y, aB.y + bB.y + 2.0f * xB.y);
            dw.z = pack2bf(aA.z + bA.z + 2.0f * xA.z, aB.z + bB.z + 2.0f * xB.z);
            dw.w = pack2bf(aA.w + bA.w + 2.0f * xA.w, aB.w + bB.w + 2.0f * xB.w);
            *reinterpret_cast<uint4*>(&s_buf[kp * SSTRIDE + c]) = dw;
            uint4 dx;
            dx.x = pack2bf(xA.x, xB.x);
            dx.y = pack2bf(xA.y, xB.y);
            dx.z = pack2bf(xA.z, xB.z);
            dx.w = pack2bf(xA.w, xB.w);
            *reinterpret_cast<uint4*>(&x_lds[kh][kp * SSTRIDE + c]) = dx;
        }
        __syncthreads();

        // partial-K MFMA (K=32): A dwords [16kh+4g .. +3]
        #pragma unroll
        for (int nt = 0; nt < 2; ++nt) {
            const int n = ln + 16 * (2 * w + nt);
            uint4 Bf;
            Bf.x = s_buf[(4 * g + 0) * SSTRIDE + n];
            Bf.y = s_buf[(4 * g + 1) * SSTRIDE + n];
            Bf.z = s_buf[(4 * g + 2) * SSTRIDE + n];
            Bf.w = s_buf[(4 * g + 3) * SSTRIDE + n];
            #pragma unroll
            for (int oc = 0; oc < 4; ++oc) {
                const int m = ln + 16 * oc;
                const uint4 A = *reinterpret_cast<const uint4*>(&w_lds[0][m][16 * kh + 4 * g]);
                D1[oc][nt] = __builtin_amdgcn_mfma_f32_16x16x32_bf16(
                    __builtin_bit_cast(short8, A), __builtin_bit_cast(short8, Bf),
                    D1[oc][nt], 0, 0, 0);
            }
        }
        __syncthreads();   // readers done before next-stage overwrite
    }

    // ---- acc = x*g (LDS-only) + GEMM2 (K-split): D2 = Wf . acc + fuse_b ----
    f32x4 D2[4][2];
    #pragma unroll
    for (int oc = 0; oc < 4; ++oc) {
        const float4 cb = *reinterpret_cast<const float4*>(&cinit[1][16 * oc + 4 * g]);
        D2[oc][0][0] = cb.x; D2[oc][0][1] = cb.y;
        D2[oc][0][2] = cb.z; D2[oc][0][3] = cb.w;
        D2[oc][1] = D2[oc][0];
    }
    #pragma unroll 1
    for (int kh = 0; kh < 2; ++kh) {
        // acc for ch [32kh,+32): x from x_lds[kh] (bf16), g from D1 regs
        #pragma unroll
        for (int nt = 0; nt < 2; ++nt) {
            const int n = ln + 16 * (2 * w + nt);
            #pragma unroll
            for (int oc2 = 0; oc2 < 2; ++oc2) {
                const int oc = 2 * kh + oc2;
                const int kpA = 8 * oc2 + 2 * g;       // rows (16oc2+4g+{0,1})/2
                const uint32_t u0 = x_lds[kh][kpA * SSTRIDE + n];
                const uint32_t u1 = x_lds[kh][(kpA + 1) * SSTRIDE + n];
                float av[4];
                av[0] = bf_lo(u0) * D1[oc][nt][0];
                av[1] = bf_hi(u0) * D1[oc][nt][1];
                av[2] = bf_lo(u1) * D1[oc][nt][2];
                av[3] = bf_hi(u1) * D1[oc][nt][3];
                s_buf[kpA * SSTRIDE + n]       = pack2bf(av[0], av[1]);
                s_buf[(kpA + 1) * SSTRIDE + n] = pack2bf(av[2], av[3]);
            }
        }
        __syncthreads();
        #pragma unroll
        for (int nt = 0; nt < 2; ++nt) {
            const int n = ln + 16 * (2 * w + nt);
            uint4 Bf;
            Bf.x = s_buf[(4 * g + 0) * SSTRIDE + n];
            Bf.y = s_buf[(4 * g + 1) * SSTRIDE + n];
            Bf.z = s_buf[(4 * g + 2) * SSTRIDE + n];
            Bf.w = s_buf[(4 * g + 3) * SSTRIDE + n];
            #pragma unroll
            for (int oc = 0; oc < 4; ++oc) {
                const int m = ln + 16 * oc;
                const uint4 A = *reinterpret_cast<const uint4*>(&w_lds[1][m][16 * kh + 4 * g]);
                D2[oc][nt] = __builtin_amdgcn_mfma_f32_16x16x32_bf16(
                    __builtin_bit_cast(short8, A), __builtin_bit_cast(short8, Bf),
                    D2[oc][nt], 0, 0, 0);
            }
        }
        __syncthreads();
    }

    // ---- epilogue: 4 chunks of 16 rows via LDS re-layout ----
    float lsum = 0.0f, lsq = 0.0f;
    {
        float* uf = reinterpret_cast<float*>(s_buf);
        const int rowin = tid >> 5;          // 0..15
        const int cl    = tid & 31;          // 32 threads x 2 float4 per row
        #pragma unroll
        for (int ck = 0; ck < 4; ++ck) {
            // fragment write: chunk rows = 16ck + (4g+j), oc = ck
            #pragma unroll
            for (int nt = 0; nt < 2; ++nt) {
                const int n = ln + 16 * (2 * w + nt);
                #pragma unroll
                for (int j = 0; j < 4; ++j)
                    uf[(4 * g + j) * SSTRIDE + n] = D2[ck][nt][j];
            }
            // resid loads issue here (hide under the barrier)
            const int m   = 16 * ck + rowin;
            const int gbm = bCL + m * Lv + col0;
            const float4 ra = *reinterpret_cast<const float4*>(&resid[gbm + 4 * cl]);
            const float4 rb = *reinterpret_cast<const float4*>(&resid[gbm + 4 * cl + 128]);
            __syncthreads();
            float4 va = *reinterpret_cast<const float4*>(&uf[rowin * SSTRIDE + 4 * cl]);
            float4 vb = *reinterpret_cast<const float4*>(&uf[rowin * SSTRIDE + 4 * cl + 128]);
            va.x = fmaxf(va.x + ra.x, 0.0f); va.y = fmaxf(va.y + ra.y, 0.0f);
            va.z = fmaxf(va.z + ra.z, 0.0f); va.w = fmaxf(va.w + ra.w, 0.0f);
            vb.x = fmaxf(vb.x + rb.x, 0.0f); vb.y = fmaxf(vb.y + rb.y, 0.0f);
            vb.z = fmaxf(vb.z + rb.z, 0.0f); vb.w = fmaxf(vb.w + rb.w, 0.0f);
            *reinterpret_cast<float4*>(&out[gbm + 4 * cl])       = va;
            *reinterpret_cast<float4*>(&out[gbm + 4 * cl + 128]) = vb;
            lsum += (va.x + va.y) + (va.z + va.w) + (vb.x + vb.y) + (vb.z + vb.w);
            lsq = fmaf(va.x, va.x, lsq); lsq = fmaf(va.y, va.y, lsq);
            lsq = fmaf(va.z, va.z, lsq); lsq = fmaf(va.w, va.w, lsq);
            lsq = fmaf(vb.x, vb.x, lsq); lsq = fmaf(vb.y, vb.y, lsq);
            lsq = fmaf(vb.z, vb.z, lsq); lsq = fmaf(vb.w, vb.w, lsq);
            __syncthreads();   // tile reads done before next chunk's writes
        }
    }

    // ---- stats: wave shuffle reduce -> 8 partials -> thread 0 ----
    #pragma unroll
    for (int st = 1; st < 64; st <<= 1) {
        lsum += __shfl_xor(lsum, st);
        lsq  += __shfl_xor(lsq,  st);
    }
    if (lane == 0) { wred[2 * w] = lsum; wred[2 * w + 1] = lsq; }
    __syncthreads();
    if (tid == 0) {
        float s = 0.0f, q = 0.0f;
        #pragma unroll
        for (int i = 0; i < 8; ++i) { s += wred[2 * i]; q += wred[2 * i + 1]; }
        partials[2 * blockIdx.x]     = s;
        partials[2 * blockIdx.x + 1] = q;
    }
}

// ---------------------------------------------------------------------------
// Pass 2: reduce 256 partials per batch -> per-(b,c) scale/bias.
// ---------------------------------------------------------------------------
__global__ __launch_bounds__(256)
void pass2(const float* __restrict__ partials, const float* __restrict__ gn_w,
           const float* __restrict__ gn_b, float* __restrict__ sb)
{
    __shared__ float r1[256], r2[256];
    __shared__ float mean_s, rs_s;
    const int b = blockIdx.x, tid = threadIdx.x;
    r1[tid] = partials[2 * (b * 256 + tid)];
    r2[tid] = partials[2 * (b * 256 + tid) + 1];
    __syncthreads();
    #pragma unroll
    for (int st = 128; st > 0; st >>= 1) {
        if (tid < st) { r1[tid] += r1[tid + st]; r2[tid] += r2[tid + st]; }
        __syncthreads();
    }
    if (tid == 0) {
        const float n = (float)Cv * (float)Lv;
        const float mean = r1[0] / n;
        const float var  = r2[0] / n - mean * mean;
        mean_s = mean;
        rs_s   = rsqrtf(var + 1e-5f);
    }
    __syncthreads();
    if (tid < Cv) {
        const float sc = gn_w[tid] * rs_s;
        sb[b * Cv + tid]           = sc;
        sb[Bv * Cv + b * Cv + tid] = fmaf(-mean_s, sc, gn_b[tid]);
    }
}

// ---------------------------------------------------------------------------
// Pass 3: in-place GroupNorm affine on d_out (float4 vectorized).
// ---------------------------------------------------------------------------
__global__ __launch_bounds__(256)
void pass3(float* __restrict__ out, const float* __restrict__ sb)
{
    const int total4 = (Bv * Cv * Lv) / 4;   // 8388608
    for (int i = blockIdx.x * blockDim.x + threadIdx.x; i < total4;
         i += gridDim.x * blockDim.x) {
        const int row = i >> 14;            // / (L/4): row = b*64 + c
        const float sc = sb[row];
        const float bi = sb[Bv * Cv + row];
        float4 v = reinterpret_cast<float4*>(out)[i];
        v.x = fmaf(v.x, sc, bi);
        v.y = fmaf(v.y, sc, bi);
        v.z = fmaf(v.z, sc, bi);
        v.w = fmaf(v.w, sc, bi);
        reinterpret_cast<float4*>(out)[i] = v;
    }
}

extern "C" void kernel_launch(void* const* d_in, const int* in_sizes, int n_in,
                              void* d_out, int out_size, void* d_ws, size_t ws_size,
                              hipStream_t stream)
{
    const float* x      = (const float*)d_in[0];
    const float* inj0   = (const float*)d_in[1];
    const float* inj1   = (const float*)d_in[2];
    const float* resid  = (const float*)d_in[3];
    const float* gate_w = (const float*)d_in[4];
    const float* gate_b = (const float*)d_in[5];
    const float* fuse_w = (const float*)d_in[6];
    const float* fuse_b = (const float*)d_in[7];
    const float* gn_w   = (const float*)d_in[8];
    const float* gn_b   = (const float*)d_in[9];

    float* out      = (float*)d_out;
    float* ws       = (float*)d_ws;
    float* partials = ws;                 // 2 * 2048 floats = 16 KiB
    float* sb       = ws + 2 * GRID1;     // 2 * 512 floats  =  4 KiB

    hipLaunchKernelGGL(pass1, dim3(GRID1), dim3(TPB), 0, stream,
                       x, inj0, inj1, resid, gate_w, gate_b, fuse_w, fuse_b,
                       out, partials);
    hipLaunchKernelGGL(pass2, dim3(Bv), dim3(256), 0, stream,
                       partials, gn_w, gn_b, sb);
    hipLaunchKernelGGL(pass3, dim3(2048), dim3(256), 0, stream, out, sb);
}

// Round 12
// 187.513 us; speedup vs baseline: 1.3098x; 1.3098x over previous
//
#include <hip/hip_runtime.h>
#include <stdint.h>

#define Bv 8
#define Cv 64
#define Lv 65536
#define TPB 512
#define COLS 256                      // contiguous cols per block (1KB/row bursts)
#define BLKS_PER_B (Lv / COLS)        // 256
#define GRID1 (Bv * BLKS_PER_B)       // 2048

// workspace: partials 2*2048 floats (16 KiB) + sb 1024 floats (4 KiB) = 20 KiB

typedef __attribute__((ext_vector_type(8))) short short8;
typedef __attribute__((ext_vector_type(4))) float f32x4;

#define SSTRIDE 260   // dwords per row: 16B-aligned, 260%32=4 staggers banks

__device__ __forceinline__ uint16_t f2bf(float f) {
    uint32_t u = __float_as_uint(f);
    uint32_t r = u + 0x7FFFu + ((u >> 16) & 1u);   // round-to-nearest-even
    return (uint16_t)(r >> 16);
}
__device__ __forceinline__ uint32_t pack2bf(float lo, float hi) {
    return (uint32_t)f2bf(lo) | ((uint32_t)f2bf(hi) << 16);
}

// ---------------------------------------------------------------------------
// Pass 1 (MFMA, M-split): out = relu(Wf·(x ⊙ (Wg·s + 2bg)) + bf + resid)
// Register law (R11 lesson): 4 waves/SIMD => 128 regs/wave; accumulators must
// stay small. M-split GEMM1 (rows 0-31 then 32-63) keeps D1 at 16 regs;
// peak = D2(32)+D1(16)=48 vs K-split's 64. s staged ONCE for all 64 ch
// (24 float4 loads in one burst = max memory-level parallelism).
// s_buf: 32 kpairs x 260 (both K-halves). a_buf: 16 kpairs (acc, per phase),
// reused as the f32 epilogue tile. No x_lds (R11's spill trigger).
// ---------------------------------------------------------------------------
__global__ void pass1(const float* __restrict__ x, const float* __restrict__ inj0,
                      const float* __restrict__ inj1, const float* __restrict__ resid,
                      const float* __restrict__ gate_w, const float* __restrict__ gate_b,
                      const float* __restrict__ fuse_w, const float* __restrict__ fuse_b,
                      float* __restrict__ out, float* __restrict__ partials)
{
    __shared__ uint32_t s_buf[32 * SSTRIDE];       // 33.3 KB, s for ch 0..63
    __shared__ uint32_t a_buf[16 * SSTRIDE];       // 16.6 KB, acc slab / epi tile
    __shared__ uint32_t w_lds[2][64][36];          // 18.4 KB
    __shared__ float cinit[2][64];                 // [0]=2*gate_b, [1]=fuse_b
    __shared__ float wred[16];                     // per-wave stats partials

    const int tid  = threadIdx.x;
    const int lane = tid & 63;
    const int w    = tid >> 6;     // wave 0..7
    const int g    = lane >> 4;    // k-group 0..3
    const int ln   = lane & 15;    // 0..15

    const int b    = blockIdx.x >> 8;
    const int lb   = blockIdx.x & 255;
    const int col0 = lb * COLS;
    const int bCL  = b * (Cv * Lv);

    // ---- stage weights + cinit (once) ----
    {
        const int mat = tid >> 8;              // 0=gate, 1=fuse
        const int m   = (tid >> 2) & 63;
        const int k0  = (tid & 3) << 4;
        const float* wsrc = mat ? fuse_w : gate_w;
        const float4* w4 = reinterpret_cast<const float4*>(wsrc + m * 64 + k0);
        uint32_t* dst = &w_lds[mat][m][k0 >> 1];
        #pragma unroll
        for (int q = 0; q < 4; ++q) {
            const float4 v = w4[q];
            dst[2 * q]     = pack2bf(v.x, v.y);
            dst[2 * q + 1] = pack2bf(v.z, v.w);
        }
        if (tid < 64) {
            cinit[0][tid] = 2.0f * gate_b[tid];
            cinit[1][tid] = fuse_b[tid];
        }
    }

    // ---- stage s = i0+i1+2x for ALL 64 ch (single burst, 24 float4 loads) --
    #pragma unroll
    for (int uu = 0; uu < 4; ++uu) {
        const int u  = tid + uu * TPB;
        const int kp = u >> 6;               // 0..31 (ch pair)
        const int c  = (u & 63) << 2;        // col 0..252
        const int rA = bCL + (2 * kp) * Lv + col0 + c;
        const int rB = rA + Lv;
        const float4 xA = *reinterpret_cast<const float4*>(x    + rA);
        const float4 aA = *reinterpret_cast<const float4*>(inj0 + rA);
        const float4 bA = *reinterpret_cast<const float4*>(inj1 + rA);
        const float4 xB = *reinterpret_cast<const float4*>(x    + rB);
        const float4 aB = *reinterpret_cast<const float4*>(inj0 + rB);
        const float4 bB = *reinterpret_cast<const float4*>(inj1 + rB);
        uint4 dw;
        dw.x = pack2bf(aA.x + bA.x + 2.0f * xA.x, aB.x + bB.x + 2.0f * xB.x);
        dw.y = pack2bf(aA.y + bA.y + 2.0f * xA.y, aB.y + bB.y + 2.0f * xB.y);
        dw.z = pack2bf(aA.z + bA.z + 2.0f * xA.z, aB.z + bB.z + 2.0f * xB.z);
        dw.w = pack2bf(aA.w + bA.w + 2.0f * xA.w, aB.w + bB.w + 2.0f * xB.w);
        *reinterpret_cast<uint4*>(&s_buf[kp * SSTRIDE + c]) = dw;
    }
    __syncthreads();   // s, weights, cinit all visible

    f32x4 D2[4][2];
    #pragma unroll
    for (int oc = 0; oc < 4; ++oc) {
        const float4 cb = *reinterpret_cast<const float4*>(&cinit[1][16 * oc + 4 * g]);
        D2[oc][0][0] = cb.x; D2[oc][0][1] = cb.y;
        D2[oc][0][2] = cb.z; D2[oc][0][3] = cb.w;
        D2[oc][1] = D2[oc][0];
    }

    float lsum = 0.0f, lsq = 0.0f;

    // ==== two M-phases: ph=0 -> gate rows 0..31, ph=1 -> rows 32..63 ====
    #pragma unroll 1
    for (int ph = 0; ph < 2; ++ph) {
        // ---- GEMM1 phase: D1 = Wg[rows] . s + 2bg  (full K, 8 MFMA) ----
        f32x4 D1[2][2];
        #pragma unroll
        for (int o2 = 0; o2 < 2; ++o2) {
            const int oc = 2 * ph + o2;
            const float4 cb = *reinterpret_cast<const float4*>(&cinit[0][16 * oc + 4 * g]);
            D1[o2][0][0] = cb.x; D1[o2][0][1] = cb.y;
            D1[o2][0][2] = cb.z; D1[o2][0][3] = cb.w;
            D1[o2][1] = D1[o2][0];
        }
        #pragma unroll
        for (int nt = 0; nt < 2; ++nt) {
            const int n = ln + 16 * (2 * w + nt);
            uint4 B0, B1;
            B0.x = s_buf[(4 * g + 0) * SSTRIDE + n];
            B0.y = s_buf[(4 * g + 1) * SSTRIDE + n];
            B0.z = s_buf[(4 * g + 2) * SSTRIDE + n];
            B0.w = s_buf[(4 * g + 3) * SSTRIDE + n];
            B1.x = s_buf[(16 + 4 * g + 0) * SSTRIDE + n];
            B1.y = s_buf[(16 + 4 * g + 1) * SSTRIDE + n];
            B1.z = s_buf[(16 + 4 * g + 2) * SSTRIDE + n];
            B1.w = s_buf[(16 + 4 * g + 3) * SSTRIDE + n];
            #pragma unroll
            for (int o2 = 0; o2 < 2; ++o2) {
                const int m = ln + 16 * (2 * ph + o2);
                const uint4 A0 = *reinterpret_cast<const uint4*>(&w_lds[0][m][4 * g]);
                const uint4 A1 = *reinterpret_cast<const uint4*>(&w_lds[0][m][16 + 4 * g]);
                D1[o2][nt] = __builtin_amdgcn_mfma_f32_16x16x32_bf16(
                    __builtin_bit_cast(short8, A0), __builtin_bit_cast(short8, B0),
                    D1[o2][nt], 0, 0, 0);
                D1[o2][nt] = __builtin_amdgcn_mfma_f32_16x16x32_bf16(
                    __builtin_bit_cast(short8, A1), __builtin_bit_cast(short8, B1),
                    D1[o2][nt], 0, 0, 0);
            }
        }

        // ---- acc = x*g for these 32 channels -> a_buf (x re-read, L2-hot) --
        #pragma unroll
        for (int nt = 0; nt < 2; ++nt) {
            const int n  = ln + 16 * (2 * w + nt);
            const int cg = bCL + col0 + n;
            #pragma unroll
            for (int o2 = 0; o2 < 2; ++o2) {
                const int m0 = 16 * (2 * ph + o2) + 4 * g;   // abs channel base
                float av[4];
                #pragma unroll
                for (int j = 0; j < 4; ++j)
                    av[j] = x[cg + (m0 + j) * Lv] * D1[o2][nt][j];
                const int kpA = 8 * o2 + 2 * g;              // within-slab pair
                a_buf[kpA * SSTRIDE + n]       = pack2bf(av[0], av[1]);
                a_buf[(kpA + 1) * SSTRIDE + n] = pack2bf(av[2], av[3]);
            }
        }
        __syncthreads();   // a_buf visible

        // ---- GEMM2 partial-K: D2 += Wf[:, kslab] . acc  (8 MFMA) ----
        #pragma unroll
        for (int nt = 0; nt < 2; ++nt) {
            const int n = ln + 16 * (2 * w + nt);
            uint4 Bf;
            Bf.x = a_buf[(4 * g + 0) * SSTRIDE + n];
            Bf.y = a_buf[(4 * g + 1) * SSTRIDE + n];
            Bf.z = a_buf[(4 * g + 2) * SSTRIDE + n];
            Bf.w = a_buf[(4 * g + 3) * SSTRIDE + n];
            #pragma unroll
            for (int oc = 0; oc < 4; ++oc) {
                const int m = ln + 16 * oc;
                const uint4 A = *reinterpret_cast<const uint4*>(&w_lds[1][m][16 * ph + 4 * g]);
                D2[oc][nt] = __builtin_amdgcn_mfma_f32_16x16x32_bf16(
                    __builtin_bit_cast(short8, A), __builtin_bit_cast(short8, Bf),
                    D2[oc][nt], 0, 0, 0);
            }
        }
        __syncthreads();   // G2 reads done before a_buf overwrite (next ph/epi)
    }

    // ---- epilogue: 4 chunks of 16 rows via a_buf re-layout ----
    {
        float* uf = reinterpret_cast<float*>(a_buf);
        const int rowin = tid >> 5;          // 0..15
        const int cl    = tid & 31;          // 32 threads x 2 float4 per row
        #pragma unroll
        for (int ck = 0; ck < 4; ++ck) {
            #pragma unroll
            for (int nt = 0; nt < 2; ++nt) {
                const int n = ln + 16 * (2 * w + nt);
                #pragma unroll
                for (int j = 0; j < 4; ++j)
                    uf[(4 * g + j) * SSTRIDE + n] = D2[ck][nt][j];
            }
            const int m   = 16 * ck + rowin;
            const int gbm = bCL + m * Lv + col0;
            const float4 ra = *reinterpret_cast<const float4*>(&resid[gbm + 4 * cl]);
            const float4 rb = *reinterpret_cast<const float4*>(&resid[gbm + 4 * cl + 128]);
            __syncthreads();
            float4 va = *reinterpret_cast<const float4*>(&uf[rowin * SSTRIDE + 4 * cl]);
            float4 vb = *reinterpret_cast<const float4*>(&uf[rowin * SSTRIDE + 4 * cl + 128]);
            va.x = fmaxf(va.x + ra.x, 0.0f); va.y = fmaxf(va.y + ra.y, 0.0f);
            va.z = fmaxf(va.z + ra.z, 0.0f); va.w = fmaxf(va.w + ra.w, 0.0f);
            vb.x = fmaxf(vb.x + rb.x, 0.0f); vb.y = fmaxf(vb.y + rb.y, 0.0f);
            vb.z = fmaxf(vb.z + rb.z, 0.0f); vb.w = fmaxf(vb.w + rb.w, 0.0f);
            *reinterpret_cast<float4*>(&out[gbm + 4 * cl])       = va;
            *reinterpret_cast<float4*>(&out[gbm + 4 * cl + 128]) = vb;
            lsum += (va.x + va.y) + (va.z + va.w) + (vb.x + vb.y) + (vb.z + vb.w);
            lsq = fmaf(va.x, va.x, lsq); lsq = fmaf(va.y, va.y, lsq);
            lsq = fmaf(va.z, va.z, lsq); lsq = fmaf(va.w, va.w, lsq);
            lsq = fmaf(vb.x, vb.x, lsq); lsq = fmaf(vb.y, vb.y, lsq);
            lsq = fmaf(vb.z, vb.z, lsq); lsq = fmaf(vb.w, vb.w, lsq);
            __syncthreads();   // tile reads done before next chunk's writes
        }
    }

    // ---- stats: wave shuffle reduce -> 8 partials -> thread 0 ----
    #pragma unroll
    for (int st = 1; st < 64; st <<= 1) {
        lsum += __shfl_xor(lsum, st);
        lsq  += __shfl_xor(lsq,  st);
    }
    if (lane == 0) { wred[2 * w] = lsum; wred[2 * w + 1] = lsq; }
    __syncthreads();
    if (tid == 0) {
        float s = 0.0f, q = 0.0f;
        #pragma unroll
        for (int i = 0; i < 8; ++i) { s += wred[2 * i]; q += wred[2 * i + 1]; }
        partials[2 * blockIdx.x]     = s;
        partials[2 * blockIdx.x + 1] = q;
    }
}

// ---------------------------------------------------------------------------
// Pass 2: reduce 256 partials per batch -> per-(b,c) scale/bias.
// ---------------------------------------------------------------------------
__global__ __launch_bounds__(256)
void pass2(const float* __restrict__ partials, const float* __restrict__ gn_w,
           const float* __restrict__ gn_b, float* __restrict__ sb)
{
    __shared__ float r1[256], r2[256];
    __shared__ float mean_s, rs_s;
    const int b = blockIdx.x, tid = threadIdx.x;
    r1[tid] = partials[2 * (b * 256 + tid)];
    r2[tid] = partials[2 * (b * 256 + tid) + 1];
    __syncthreads();
    #pragma unroll
    for (int st = 128; st > 0; st >>= 1) {
        if (tid < st) { r1[tid] += r1[tid + st]; r2[tid] += r2[tid + st]; }
        __syncthreads();
    }
    if (tid == 0) {
        const float n = (float)Cv * (float)Lv;
        const float mean = r1[0] / n;
        const float var  = r2[0] / n - mean * mean;
        mean_s = mean;
        rs_s   = rsqrtf(var + 1e-5f);
    }
    __syncthreads();
    if (tid < Cv) {
        const float sc = gn_w[tid] * rs_s;
        sb[b * Cv + tid]           = sc;
        sb[Bv * Cv + b * Cv + tid] = fmaf(-mean_s, sc, gn_b[tid]);
    }
}

// ---------------------------------------------------------------------------
// Pass 3: in-place GroupNorm affine on d_out (float4 vectorized).
// ---------------------------------------------------------------------------
__global__ __launch_bounds__(256)
void pass3(float* __restrict__ out, const float* __restrict__ sb)
{
    const int total4 = (Bv * Cv * Lv) / 4;   // 8388608
    for (int i = blockIdx.x * blockDim.x + threadIdx.x; i < total4;
         i += gridDim.x * blockDim.x) {
        const int row = i >> 14;            // / (L/4): row = b*64 + c
        const float sc = sb[row];
        const float bi = sb[Bv * Cv + row];
        float4 v = reinterpret_cast<float4*>(out)[i];
        v.x = fmaf(v.x, sc, bi);
        v.y = fmaf(v.y, sc, bi);
        v.z = fmaf(v.z, sc, bi);
        v.w = fmaf(v.w, sc, bi);
        reinterpret_cast<float4*>(out)[i] = v;
    }
}

extern "C" void kernel_launch(void* const* d_in, const int* in_sizes, int n_in,
                              void* d_out, int out_size, void* d_ws, size_t ws_size,
                              hipStream_t stream)
{
    const float* x      = (const float*)d_in[0];
    const float* inj0   = (const float*)d_in[1];
    const float* inj1   = (const float*)d_in[2];
    const float* resid  = (const float*)d_in[3];
    const float* gate_w = (const float*)d_in[4];
    const float* gate_b = (const float*)d_in[5];
    const float* fuse_w = (const float*)d_in[6];
    const float* fuse_b = (const float*)d_in[7];
    const float* gn_w   = (const float*)d_in[8];
    const float* gn_b   = (const float*)d_in[9];

    float* out      = (float*)d_out;
    float* ws       = (float*)d_ws;
    float* partials = ws;                 // 2 * 2048 floats = 16 KiB
    float* sb       = ws + 2 * GRID1;     // 2 * 512 floats  =  4 KiB

    hipLaunchKernelGGL(pass1, dim3(GRID1), dim3(TPB), 0, stream,
                       x, inj0, inj1, resid, gate_w, gate_b, fuse_w, fuse_b,
                       out, partials);
    hipLaunchKernelGGL(pass2, dim3(Bv), dim3(256), 0, stream,
                       partials, gn_w, gn_b, sb);
    hipLaunchKernelGGL(pass3, dim3(2048), dim3(256), 0, stream, out, sb);
}